// Round 2
// baseline (513.865 us; speedup 1.0000x reference)
//
#include <hip/hip_runtime.h>

// DetectionLayer decode, fp32, N=2M rows x C=85 cols.
// out[r][0:2] = in[r][0:2]*an[r][2:4] + an[r][0:2]
// out[r][2:4] = exp(in[r][2:4])*an[r][2:4]
// out[r][4:]  = in[r][4:]
// row zeroed when in[r][5] <= 0.5
//
// Memory-bound stream (~1.39 GB traffic, ~220 us floor @ 6.3 TB/s).
// Structure: flat float4 grid-stride. A float4 starting at col c is pure
// passthrough iff 4 <= c <= 81 (no decode col, no row crossing) — ~91% of
// iterations take that branch-light path (div + cond load + 4 muls). The
// remaining ~9% handle decode/crossing once per iteration with native
// __expf. This cuts ~385 VALU instrs/wave-iter (round-1 rocprof) to ~70.

#ifndef DET_C
#define DET_C 85u
#endif

__global__ __launch_bounds__(256) void DetectionLayer_kernel(
    const float* __restrict__ in,       // [N*C]
    const float* __restrict__ anchors,  // [N*4]
    float* __restrict__ out,            // [N*C]
    unsigned int n_elem,                // N*C
    unsigned int n4)                    // n_elem/4
{
    const unsigned int stride = gridDim.x * blockDim.x;
    const unsigned int tid = blockIdx.x * blockDim.x + threadIdx.x;

    for (unsigned int i4 = tid; i4 < n4; i4 += stride) {
        const unsigned int base = i4 * 4u;
        const unsigned int r = base / DET_C;    // compile-time const -> magic mul
        const unsigned int c = base - r * DET_C;

        float4 v = reinterpret_cast<const float4*>(in)[i4];
        float4 o;

        if (c >= 4u && c <= (DET_C - 4u)) {
            // Fast path: all 4 elements same row, all passthrough.
            const float condf = in[r * DET_C + 5u] > 0.5f ? 1.0f : 0.0f;
            o.x = v.x * condf;
            o.y = v.y * condf;
            o.z = v.z * condf;
            o.w = v.w * condf;
        } else {
            // Slow path: decode columns and/or row crossing (~9% of iters).
            float vv[4] = {v.x, v.y, v.z, v.w};
            float oo[4];
#pragma unroll
            for (int k = 0; k < 4; ++k) {
                unsigned int cc = c + (unsigned int)k;
                unsigned int rr = r;
                if (cc >= DET_C) { cc -= DET_C; ++rr; }   // at most one crossing
                const bool cond = in[rr * DET_C + 5u] > 0.5f;
                float dec;
                if (cc < 2u) {
                    dec = vv[k] * anchors[rr * 4u + 2u + cc] + anchors[rr * 4u + cc];
                } else if (cc < 4u) {
                    dec = __expf(vv[k]) * anchors[rr * 4u + cc];
                } else {
                    dec = vv[k];
                }
                oo[k] = cond ? dec : 0.0f;
            }
            o = make_float4(oo[0], oo[1], oo[2], oo[3]);
        }

        reinterpret_cast<float4*>(out)[i4] = o;
    }

    // Scalar tail (not hit for N*C = 170M, divisible by 4; kept for safety).
    for (unsigned int i = n4 * 4u + tid; i < n_elem; i += stride) {
        const unsigned int r = i / DET_C;
        const unsigned int c = i - r * DET_C;
        const bool cond = in[r * DET_C + 5u] > 0.5f;
        const float val = in[i];
        float dec;
        if (c < 2u) {
            dec = val * anchors[r * 4u + 2u + c] + anchors[r * 4u + c];
        } else if (c < 4u) {
            dec = __expf(val) * anchors[r * 4u + c];
        } else {
            dec = val;
        }
        out[i] = cond ? dec : 0.0f;
    }
}

extern "C" void kernel_launch(void* const* d_in, const int* in_sizes, int n_in,
                              void* d_out, int out_size, void* d_ws, size_t ws_size,
                              hipStream_t stream) {
    const float* in      = (const float*)d_in[0];   // [N, 85] fp32
    const float* anchors = (const float*)d_in[1];   // [N, 4]  fp32
    float* out = (float*)d_out;

    const unsigned int n_elem = (unsigned int)in_sizes[0];   // N*C
    const unsigned int n4 = n_elem / 4u;

    const int block = 256;
    unsigned int want = (n4 + block - 1) / block;
    unsigned int grid = want < 2048u ? (want ? want : 1u) : 2048u;

    DetectionLayer_kernel<<<grid, block, 0, stream>>>(in, anchors, out, n_elem, n4);
}

// Round 3
// 460.449 us; speedup vs baseline: 1.1160x; 1.1160x over previous
//
#include <hip/hip_runtime.h>

// DetectionLayer decode, fp32, N=2M rows x C=85 cols. Row-per-thread.
// out[r][0:2] = in[r][0:2]*an[r][2:4] + an[r][0:2]
// out[r][2:4] = exp(in[r][2:4])*an[r][2:4]
// out[r][4:]  = in[r][4:]
// row zeroed when in[r][5] <= 0.5
//
// Round-1/2 lesson: flat float4 grid-stride was LATENCY-bound (1 load in
// flight, VGPR=12, divergent decode path every wave). Here each thread owns
// one row: no divergence at all, cond/anchors are row-local registers, and
// all 22 row loads issue before the first dependent use (deep MLP). Lane
// stride is 340B but a wave's loads cover one contiguous 21.7KB region, so
// every line is fully consumed (fits L1).

typedef float f4 __attribute__((ext_vector_type(4)));
typedef f4 __attribute__((aligned(4))) f4u;   // row base is only 4B-aligned (r*340)

__global__ __launch_bounds__(256) void DetectionLayer_kernel(
    const float* __restrict__ in,       // [N*85]
    const float* __restrict__ anchors,  // [N*4]
    float* __restrict__ out,            // [N*85]
    unsigned int N)
{
    const unsigned int r = blockIdx.x * blockDim.x + threadIdx.x;
    if (r >= N) return;

    const float* rp = in  + (size_t)r * 85u;
    float*       op = out + (size_t)r * 85u;

    // Issue ALL row loads up front — 22 independent VMEM ops in flight.
    f4 x0 = *(const f4u*)(rp);        // cols 0..3  (decode)
    f4 x1 = *(const f4u*)(rp + 4);    // cols 4..7  (col 5 = score)
    f4 an = *(const f4u*)(anchors + 4u * r);   // 16B-aligned, coalesced

    f4 b[10];                         // cols 8..47
#pragma unroll
    for (int k = 0; k < 10; ++k) b[k] = *(const f4u*)(rp + 8 + 4 * k);

    f4 c[9];                          // cols 48..83
#pragma unroll
    for (int k = 0; k < 9; ++k) c[k] = *(const f4u*)(rp + 48 + 4 * k);

    const float last = rp[84];        // col 84

    // First dependent use: cond from x1.y (col 5).
    const float condf = x1.y > 0.5f ? 1.0f : 0.0f;

    f4 o0;
    o0.x = (x0.x * an.z + an.x) * condf;     // pred_y
    o0.y = (x0.y * an.w + an.y) * condf;     // pred_x
    o0.z = __expf(x0.z) * an.z * condf;      // pred_h
    o0.w = __expf(x0.w) * an.w * condf;      // pred_w
    *(f4u*)op       = o0;
    *(f4u*)(op + 4) = x1 * condf;

#pragma unroll
    for (int k = 0; k < 10; ++k) *(f4u*)(op + 8  + 4 * k) = b[k] * condf;
#pragma unroll
    for (int k = 0; k < 9;  ++k) *(f4u*)(op + 48 + 4 * k) = c[k] * condf;
    op[84] = last * condf;
}

extern "C" void kernel_launch(void* const* d_in, const int* in_sizes, int n_in,
                              void* d_out, int out_size, void* d_ws, size_t ws_size,
                              hipStream_t stream) {
    const float* in      = (const float*)d_in[0];   // [N, 85] fp32
    const float* anchors = (const float*)d_in[1];   // [N, 4]  fp32
    float* out = (float*)d_out;

    const unsigned int N = (unsigned int)(in_sizes[0] / 85);  // 2,000,000

    const int block = 256;
    const unsigned int grid = (N + block - 1) / block;        // 7813 blocks

    DetectionLayer_kernel<<<grid, block, 0, stream>>>(in, anchors, out, N);
}

// Round 4
// 255.393 us; speedup vs baseline: 2.0121x; 1.8029x over previous
//
#include <hip/hip_runtime.h>

// DetectionLayer decode, fp32, N=2M rows x C=85 cols.
// out[r][0:2] = in[r][0:2]*an[r][2:4] + an[r][0:2]
// out[r][2:4] = exp(in[r][2:4])*an[r][2:4]
// out[r][4:]  = in[r][4:]   ; row zeroed when in[r][5] <= 0.5
//
// Round-3 lesson: row-per-thread stores (4B-aligned, 340B lane stride) caused
// 1.46x HBM write amplification (995 MB vs 680 MB ideal) via partial-line
// eviction RMW. This version stages a 64-row chunk in LDS so BOTH global
// streams are flat, 16B-aligned, full-line coalesced float4; decode happens
// in LDS. 22KB LDS -> 7 blocks/CU, 28 waves/CU.

typedef float f4 __attribute__((ext_vector_type(4)));

#define DET_C   85u
#define ROWS    64u                  // rows per block
#define ELEMS   (DET_C * ROWS)       // 5440 floats per block
#define NF4     (ELEMS / 4u)         // 1360 float4 per block (= 5*256 + 80)

__global__ __launch_bounds__(256) void DetectionLayer_kernel(
    const float* __restrict__ in,       // [N*85]
    const float* __restrict__ anchors,  // [N*4]
    float* __restrict__ out,            // [N*85]
    unsigned int N)
{
    __shared__ f4 lds4[NF4];
    __shared__ float cf[ROWS];
    float* ldsf = (float*)lds4;

    const unsigned int tid  = threadIdx.x;
    const unsigned int row0 = blockIdx.x * ROWS;
    const unsigned int nrows = (N - row0 < ROWS) ? (N - row0) : ROWS;

    const size_t ebase = (size_t)row0 * DET_C;          // element base, *4B is 16B-aligned
    const f4* in4  = (const f4*)(in  + ebase);
    f4*       out4 = (f4*)(out + ebase);

    if (nrows == ROWS) {
        // ---- full block fast path ----
        // anchors: one coalesced float4 per row-owner lane, issued early
        f4 an;
        if (tid < ROWS)
            an = *(const f4*)(anchors + (size_t)(row0 + tid) * 4u);

        // phase 1: stage 64 rows, flat coalesced float4 (6 indep loads/thread)
#pragma unroll
        for (unsigned int k = 0; k < 5; ++k)
            lds4[tid + k * 256u] = in4[tid + k * 256u];
        if (tid < NF4 - 5u * 256u)                       // tid < 80
            lds4[tid + 1280u] = in4[tid + 1280u];
        __syncthreads();

        // phase 2: decode cols 0..3 in LDS, publish cond per row
        if (tid < ROWS) {
            const unsigned int o = tid * DET_C;
            const float x0 = ldsf[o + 0], x1 = ldsf[o + 1];
            const float x2 = ldsf[o + 2], x3 = ldsf[o + 3];
            cf[tid] = ldsf[o + 5] > 0.5f ? 1.0f : 0.0f;
            ldsf[o + 0] = x0 * an.z + an.x;              // pred_y
            ldsf[o + 1] = x1 * an.w + an.y;              // pred_x
            ldsf[o + 2] = __expf(x2) * an.z;             // pred_h
            ldsf[o + 3] = __expf(x3) * an.w;             // pred_w
        }
        __syncthreads();

        // phase 3: masked flat write-out, full-line coalesced
#pragma unroll
        for (unsigned int k = 0; k < 6; ++k) {
            const unsigned int i = tid + k * 256u;
            if (k == 5 && i >= NF4) break;
            f4 v = lds4[i];
            const unsigned int e0 = i * 4u;
            const unsigned int rl = e0 / DET_C;          // const 85 -> magic mul
            const unsigned int c0 = e0 - rl * DET_C;
            const float m0 = cf[rl];
            // at most one row crossing inside a float4
            v.x *= m0;
            v.y *= (c0 + 1u >= DET_C) ? cf[rl + 1u] : m0;
            v.z *= (c0 + 2u >= DET_C) ? cf[rl + 1u] : m0;
            v.w *= (c0 + 3u >= DET_C) ? cf[rl + 1u] : m0;
            out4[i] = v;
        }
    } else {
        // ---- partial tail block (never hit for N=2M; kept for safety) ----
        const unsigned int nelem = nrows * DET_C;
        for (unsigned int e = tid; e < nelem; e += 256u) {
            const unsigned int rl = e / DET_C;
            const unsigned int cc = e - rl * DET_C;
            const size_t grow = (size_t)(row0 + rl);
            const float condf = in[grow * DET_C + 5u] > 0.5f ? 1.0f : 0.0f;
            const float val = in[ebase + e];
            const float* ap = anchors + grow * 4u;
            float dec;
            if (cc < 2u)      dec = val * ap[2u + cc] + ap[cc];
            else if (cc < 4u) dec = __expf(val) * ap[cc];
            else              dec = val;
            out[ebase + e] = dec * condf;
        }
    }
}

extern "C" void kernel_launch(void* const* d_in, const int* in_sizes, int n_in,
                              void* d_out, int out_size, void* d_ws, size_t ws_size,
                              hipStream_t stream) {
    const float* in      = (const float*)d_in[0];   // [N, 85] fp32
    const float* anchors = (const float*)d_in[1];   // [N, 4]  fp32
    float* out = (float*)d_out;

    const unsigned int N = (unsigned int)(in_sizes[0] / 85);  // 2,000,000
    const unsigned int grid = (N + ROWS - 1) / ROWS;          // 31250 blocks

    DetectionLayer_kernel<<<grid, 256, 0, stream>>>(in, anchors, out, N);
}

// Round 5
// 249.666 us; speedup vs baseline: 2.0582x; 1.0229x over previous
//
#include <hip/hip_runtime.h>

// DetectionLayer decode, fp32, N=2M rows x C=85 cols.
// out[r][0:2] = in[r][0:2]*an[r][2:4] + an[r][0:2]
// out[r][2:4] = exp(in[r][2:4])*an[r][2:4]
// out[r][4:]  = in[r][4:]   ; row zeroed when in[r][5] <= 0.5
//
// Round-4 structure (LDS-staged 64-row chunk, flat coalesced float4 both
// directions) hit 255 us = 87% of the 6.29 TB/s copy ceiling. Round-5 change:
// NON-TEMPORAL stores for the output stream (written once, never read) so the
// 680 MB write stream stops evicting the input stream's L3 residue between
// replays — targets the HBM fetch side, write side unchanged.

typedef float f4 __attribute__((ext_vector_type(4)));

#define DET_C   85u
#define ROWS    64u                  // rows per block
#define ELEMS   (DET_C * ROWS)       // 5440 floats per block
#define NF4     (ELEMS / 4u)         // 1360 float4 per block (= 5*256 + 80)

__global__ __launch_bounds__(256) void DetectionLayer_kernel(
    const float* __restrict__ in,       // [N*85]
    const float* __restrict__ anchors,  // [N*4]
    float* __restrict__ out,            // [N*85]
    unsigned int N)
{
    __shared__ f4 lds4[NF4];
    __shared__ float cf[ROWS];
    float* ldsf = (float*)lds4;

    const unsigned int tid  = threadIdx.x;
    const unsigned int row0 = blockIdx.x * ROWS;
    const unsigned int nrows = (N - row0 < ROWS) ? (N - row0) : ROWS;

    const size_t ebase = (size_t)row0 * DET_C;          // element base, *4B is 16B-aligned
    const f4* in4  = (const f4*)(in  + ebase);
    f4*       out4 = (f4*)(out + ebase);

    if (nrows == ROWS) {
        // ---- full block fast path ----
        // anchors: one coalesced float4 per row-owner lane, issued early
        f4 an;
        if (tid < ROWS)
            an = *(const f4*)(anchors + (size_t)(row0 + tid) * 4u);

        // phase 1: stage 64 rows, flat coalesced float4 (6 indep loads/thread)
#pragma unroll
        for (unsigned int k = 0; k < 5; ++k)
            lds4[tid + k * 256u] = in4[tid + k * 256u];
        if (tid < NF4 - 5u * 256u)                       // tid < 80
            lds4[tid + 1280u] = in4[tid + 1280u];
        __syncthreads();

        // phase 2: decode cols 0..3 in LDS, publish cond per row
        if (tid < ROWS) {
            const unsigned int o = tid * DET_C;
            const float x0 = ldsf[o + 0], x1 = ldsf[o + 1];
            const float x2 = ldsf[o + 2], x3 = ldsf[o + 3];
            cf[tid] = ldsf[o + 5] > 0.5f ? 1.0f : 0.0f;
            ldsf[o + 0] = x0 * an.z + an.x;              // pred_y
            ldsf[o + 1] = x1 * an.w + an.y;              // pred_x
            ldsf[o + 2] = __expf(x2) * an.z;             // pred_h
            ldsf[o + 3] = __expf(x3) * an.w;             // pred_w
        }
        __syncthreads();

        // phase 3: masked flat write-out, full-line coalesced, non-temporal
#pragma unroll
        for (unsigned int k = 0; k < 6; ++k) {
            const unsigned int i = tid + k * 256u;
            if (k == 5 && i >= NF4) break;
            f4 v = lds4[i];
            const unsigned int e0 = i * 4u;
            const unsigned int rl = e0 / DET_C;          // const 85 -> magic mul
            const unsigned int c0 = e0 - rl * DET_C;
            const float m0 = cf[rl];
            // at most one row crossing inside a float4
            v.x *= m0;
            v.y *= (c0 + 1u >= DET_C) ? cf[rl + 1u] : m0;
            v.z *= (c0 + 2u >= DET_C) ? cf[rl + 1u] : m0;
            v.w *= (c0 + 3u >= DET_C) ? cf[rl + 1u] : m0;
            __builtin_nontemporal_store(v, &out4[i]);
        }
    } else {
        // ---- partial tail block (never hit for N=2M; kept for safety) ----
        const unsigned int nelem = nrows * DET_C;
        for (unsigned int e = tid; e < nelem; e += 256u) {
            const unsigned int rl = e / DET_C;
            const unsigned int cc = e - rl * DET_C;
            const size_t grow = (size_t)(row0 + rl);
            const float condf = in[grow * DET_C + 5u] > 0.5f ? 1.0f : 0.0f;
            const float val = in[ebase + e];
            const float* ap = anchors + grow * 4u;
            float dec;
            if (cc < 2u)      dec = val * ap[2u + cc] + ap[cc];
            else if (cc < 4u) dec = __expf(val) * ap[cc];
            else              dec = val;
            __builtin_nontemporal_store(dec * condf, &out[ebase + e]);
        }
    }
}

extern "C" void kernel_launch(void* const* d_in, const int* in_sizes, int n_in,
                              void* d_out, int out_size, void* d_ws, size_t ws_size,
                              hipStream_t stream) {
    const float* in      = (const float*)d_in[0];   // [N, 85] fp32
    const float* anchors = (const float*)d_in[1];   // [N, 4]  fp32
    float* out = (float*)d_out;

    const unsigned int N = (unsigned int)(in_sizes[0] / 85);  // 2,000,000
    const unsigned int grid = (N + ROWS - 1) / ROWS;          // 31250 blocks

    DetectionLayer_kernel<<<grid, 256, 0, stream>>>(in, anchors, out, N);
}